// Round 23
// baseline (185.106 us; speedup 1.0000x reference)
//
#include <hip/hip_runtime.h>
#include <hip/hip_bf16.h>
#include <cstdint>

typedef __attribute__((ext_vector_type(8))) short bf16x8;
typedef __attribute__((ext_vector_type(4))) float f32x4;
typedef __attribute__((ext_vector_type(2))) float f32x2;

__device__ inline uint16_t f2bf(float f) {
  uint32_t u = __float_as_uint(f);
  u += 0x7FFF + ((u >> 16) & 1);          // round-to-nearest-even
  return (uint16_t)(u >> 16);
}
// HW pair-pack: dst = [hi.bf16 : lo.bf16], RNE. Register-only asm (no mem hazard).
__device__ inline uint32_t cvtpk(float lo, float hi) {
  uint32_t r;
  asm("v_cvt_pk_bf16_f32 %0, %1, %2" : "=v"(r) : "v"(lo), "v"(hi));
  return r;
}

// ---------------- prep1a: parallel affine dots (16 blocks) ----------------
__global__ __launch_bounds__(256) void prep1a_kernel(
    const float* __restrict__ w,        // (2,512)
    const float* __restrict__ afw,      // (128,512)
    const float* __restrict__ afb,      // (128)
    const float* __restrict__ argbw,    // (128,512)
    const float* __restrict__ argbb,    // (128)
    const float* __restrict__ ema_r,    // (1)
    float* __restrict__ sfeat_ws,       // (256)
    float* __restrict__ srgb_ws,        // (256)
    float* __restrict__ partial)        // (16)
{
  __shared__ float psum[4];
  const int g = blockIdx.x;
  const int tid = threadIdx.x, lane = tid & 63, wv = tid >> 6;
  const float wg = 0.04419417382415922f;    // 1/sqrt(512)
  const float er = rsqrtf(ema_r[0]);
  float mysq = 0.f;
  #pragma unroll
  for (int i = 0; i < 4; ++i) {
    const int p = g*16 + wv*4 + i;
    const int bb = p >> 7, c = p & 127;
    float d1 = 0.f, d2 = 0.f;
    #pragma unroll
    for (int it = 0; it < 8; ++it) {
      const int k = lane + 64*it;
      const float wvv = w[bb*512 + k];
      d1 += wvv * afw[c*512 + k];
      d2 += wvv * argbw[c*512 + k];
    }
    #pragma unroll
    for (int off = 32; off; off >>= 1) {
      d1 += __shfl_xor(d1, off, 64);
      d2 += __shfl_xor(d2, off, 64);
    }
    const float sfeat = d1 * wg + afb[c];
    if (lane == 0) {
      sfeat_ws[p] = sfeat;
      srgb_ws[p]  = (d2 * wg + argbb[c]) * 0.08838834764831845f * er;
      mysq += sfeat * sfeat;
    }
  }
  if (lane == 0) psum[wv] = mysq;
  __syncthreads();
  if (tid == 0) partial[g] = psum[0] + psum[1] + psum[2] + psum[3];
}

// ---------------- prep1b: normalize s_feat + build rgb coefs ----------------
__global__ __launch_bounds__(256) void prep1b_kernel(
    const float* __restrict__ sfeat_ws, const float* __restrict__ srgb_ws,
    const float* __restrict__ wrgb, const float* __restrict__ partial,
    float* __restrict__ s_feat_out, float* __restrict__ coef_out)
{
  __shared__ float snorm_s;
  const int tid = threadIdx.x;
  if (tid == 0) {
    float s = 0.f;
    #pragma unroll
    for (int gg = 0; gg < 16; ++gg) s += partial[gg];
    snorm_s = rsqrtf(s * (1.0f/256.0f));
  }
  __syncthreads();
  const float snorm = snorm_s;
  s_feat_out[tid] = sfeat_ws[tid] * snorm;
  for (int e = tid; e < 768; e += 256) {
    int bb = e / 384, o = (e % 384) / 128, i = e & 127;
    coef_out[e] = wrgb[o*128 + i] * srgb_ws[bb*128 + i];
  }
}

// ---------------- prep2: wnscale (inline) + modulate + demod -> bf16 fragments ----------------
__global__ __launch_bounds__(128) void prep2_kernel(
    const float* __restrict__ wfeat, const float* __restrict__ s_feat,
    const float* __restrict__ ema_f, short* __restrict__ wfrag)
{
  __shared__ float red[128];
  const int bo = blockIdx.x, b = bo >> 7, o = bo & 127;
  const int i = threadIdx.x;
  float wraw[9]; float ssr = 0.f;
  #pragma unroll
  for (int j = 0; j < 9; ++j) { wraw[j] = wfeat[(o*128 + i)*9 + j]; ssr += wraw[j]*wraw[j]; }
  red[i] = ssr; __syncthreads();
  for (int off = 64; off > 0; off >>= 1) { if (i < off) red[i] += red[i+off]; __syncthreads(); }
  const float wsc = rsqrtf(red[0] * (1.0f/1152.0f));
  const float sv = s_feat[b*128 + i];
  float wr[9]; float ss = 0.f;
  #pragma unroll
  for (int j = 0; j < 9; ++j) { wr[j] = wraw[j] * wsc * sv; ss += wr[j]*wr[j]; }
  __syncthreads();
  red[i] = ss; __syncthreads();
  for (int off = 64; off > 0; off >>= 1) { if (i < off) red[i] += red[i+off]; __syncthreads(); }
  const float d = rsqrtf(red[0] + 1e-8f) * rsqrtf(ema_f[0]);
  const int chunk = i >> 5;
  const int lane = (o & 15) | (((i >> 3) & 3) << 4);
  const int jj = i & 7;
  #pragma unroll
  for (int tap = 0; tap < 9; ++tap) {
    int kidx = chunk*9 + tap;
    size_t sidx = ((((size_t)b*36 + kidx)*8 + (o >> 4)) << 9) + (lane << 3) + jj;
    wfrag[sidx] = (short)f2bf(wr[tap] * d);
  }
}

// ---------------- conv via bf16 MFMA implicit GEMM ----------------
// (byte-identical to round 21)
__global__ __launch_bounds__(256, 3) void conv_mfma_kernel(
    const float* __restrict__ x, const short* __restrict__ wfrag,
    const float* __restrict__ bias_feat, uint16_t* __restrict__ conv_outb)
{
  __shared__ __align__(16) char xls[52224];
  __shared__ float bias_lds[128];
  const int tid = threadIdx.x;
  const int bx = blockIdx.x, by = blockIdx.y, b = blockIdx.z;
  const int x0 = bx * 32, y0 = by * 4;
  if (tid < 128) bias_lds[tid] = bias_feat[tid];

  const f32x4 f4z = {0.f, 0.f, 0.f, 0.f};
  const float* xb = x + (size_t)b * 8388608;

  {
    const int sl = tid & 7, pL = tid >> 3;
    const int gxm = x0 + 4*sl;
    const bool xokm = (unsigned)gxm <= 252u;
    const int gxe = x0 - 2;
    #pragma unroll
    for (int r = 0; r < 6; ++r) {
      const int gy = y0 - 2 + r;
      const bool yok = (unsigned)gy < 256u;
      #pragma unroll
      for (int ph = 0; ph < 2; ++ph) {
        const int p = pL + 32*ph;
        const float* s0 = xb + (size_t)(2*p)*65536 + gy*256 + gxm;
        const bool ok = yok && xokm;
        f32x4 v0 = ok ? *(const f32x4*)s0 : f4z;
        f32x4 v1 = ok ? *(const f32x4*)(s0 + 65536) : f4z;
        char* wb = xls + (size_t)(((r*16 + (p>>2))*34 + 2 + 4*sl)*16 + (p&3)*4);
        #pragma unroll
        for (int i2 = 0; i2 < 4; ++i2)
          *(uint32_t*)(wb + i2*16) = cvtpk(v0[i2], v1[i2]);
        if (sl == 0) {
          const bool eok = yok && (gxe >= 0);
          const float* e0 = xb + (size_t)(2*p)*65536 + gy*256 + gxe;
          float e00 = eok ? e0[0] : 0.f, e01 = eok ? e0[1] : 0.f;
          float e10 = eok ? e0[65536] : 0.f, e11 = eok ? e0[65537] : 0.f;
          char* eb = xls + (size_t)(((r*16 + (p>>2))*34)*16 + (p&3)*4);
          *(uint32_t*)eb        = cvtpk(e00, e10);
          *(uint32_t*)(eb + 16) = cvtpk(e01, e11);
        }
      }
    }
  }
  __syncthreads();

  const int lane = tid & 63, wave = tid >> 6;
  const int wp = wave & 1, wo = wave >> 1;
  const int l15 = lane & 15, lq = lane >> 4;
  const short* wbase = wfrag + ((size_t)b*288 + wo*4)*512 + (size_t)lane*8;
  const int abase = ((wp*32 + lq)*34 + l15)*16;

  f32x4 acc[4][4] = {};
  bf16x8 wfA[4], wfB[4], wfC[4];

#define LDW(KI, WF) { const short* wp_ = wbase + (size_t)(KI)*4096;          \
    WF[0] = *(const bf16x8*)(wp_);       WF[1] = *(const bf16x8*)(wp_+512);  \
    WF[2] = *(const bf16x8*)(wp_+1024);  WF[3] = *(const bf16x8*)(wp_+1536); }

#define MFX(KI, WF) {                                                         \
    const int ch_ = (KI)/9, tp_ = (KI)%9, ky_ = tp_/3, kx_ = tp_%3;           \
    const int o00 = ((ky_*16 + ch_*4)*34 + kx_)*16;                           \
    const int o10 = o00 + 8704;                                               \
    bf16x8 xf0 = *(const bf16x8*)(xls + abase + o00);                         \
    bf16x8 xf1 = *(const bf16x8*)(xls + abase + o00 + 256);                   \
    bf16x8 xf2 = *(const bf16x8*)(xls + abase + o10);                         \
    bf16x8 xf3 = *(const bf16x8*)(xls + abase + o10 + 256);                   \
    __builtin_amdgcn_s_setprio(1);                                            \
    acc[0][0] = __builtin_amdgcn_mfma_f32_16x16x32_bf16(xf0, WF[0], acc[0][0], 0,0,0); \
    acc[0][1] = __builtin_amdgcn_mfma_f32_16x16x32_bf16(xf0, WF[1], acc[0][1], 0,0,0); \
    acc[0][2] = __builtin_amdgcn_mfma_f32_16x16x32_bf16(xf0, WF[2], acc[0][2], 0,0,0); \
    acc[0][3] = __builtin_amdgcn_mfma_f32_16x16x32_bf16(xf0, WF[3], acc[0][3], 0,0,0); \
    acc[1][0] = __builtin_amdgcn_mfma_f32_16x16x32_bf16(xf1, WF[0], acc[1][0], 0,0,0); \
    acc[1][1] = __builtin_amdgcn_mfma_f32_16x16x32_bf16(xf1, WF[1], acc[1][1], 0,0,0); \
    acc[1][2] = __builtin_amdgcn_mfma_f32_16x16x32_bf16(xf1, WF[2], acc[1][2], 0,0,0); \
    acc[1][3] = __builtin_amdgcn_mfma_f32_16x16x32_bf16(xf1, WF[3], acc[1][3], 0,0,0); \
    acc[2][0] = __builtin_amdgcn_mfma_f32_16x16x32_bf16(xf2, WF[0], acc[2][0], 0,0,0); \
    acc[2][1] = __builtin_amdgcn_mfma_f32_16x16x32_bf16(xf2, WF[1], acc[2][1], 0,0,0); \
    acc[2][2] = __builtin_amdgcn_mfma_f32_16x16x32_bf16(xf2, WF[2], acc[2][2], 0,0,0); \
    acc[2][3] = __builtin_amdgcn_mfma_f32_16x16x32_bf16(xf2, WF[3], acc[2][3], 0,0,0); \
    acc[3][0] = __builtin_amdgcn_mfma_f32_16x16x32_bf16(xf3, WF[0], acc[3][0], 0,0,0); \
    acc[3][1] = __builtin_amdgcn_mfma_f32_16x16x32_bf16(xf3, WF[1], acc[3][1], 0,0,0); \
    acc[3][2] = __builtin_amdgcn_mfma_f32_16x16x32_bf16(xf3, WF[2], acc[3][2], 0,0,0); \
    acc[3][3] = __builtin_amdgcn_mfma_f32_16x16x32_bf16(xf3, WF[3], acc[3][3], 0,0,0); \
    __builtin_amdgcn_s_setprio(0); }

  LDW(0, wfA); LDW(1, wfB); LDW(2, wfC);
  #pragma unroll
  for (int kk = 0; kk < 36; kk += 3) {
    MFX(kk, wfA);
    if (kk + 3 < 36) LDW(kk + 3, wfA);
    MFX(kk + 1, wfB);
    if (kk + 4 < 36) LDW(kk + 4, wfB);
    MFX(kk + 2, wfC);
    if (kk + 5 < 36) LDW(kk + 5, wfC);
  }
#undef LDW
#undef MFX

  // epilogue: bf16 pack via cvt_pk, aligned uint2 stores (row stride 260)
  #pragma unroll
  for (int p = 0; p < 4; ++p) {
    const int py = y0 + wp*2 + (p>>1);
    if (py >= 258) continue;
    const int px0 = x0 + (p&1)*16 + lq*4;
    #pragma unroll
    for (int o = 0; o < 4; ++o) {
      const int oc = wo*64 + o*16 + l15;
      const float bz = bias_lds[oc];
      f32x4 v = acc[p][o];
      v[0] += bz; v[1] += bz; v[2] += bz; v[3] += bz;
      uint16_t* dst = conv_outb + (size_t)(b*128 + oc)*67080 + (size_t)py*260 + px0;
      uint32_t w0 = cvtpk(v[0], v[1]);
      if (px0 <= 254) {
        uint2 pk; pk.x = w0; pk.y = cvtpk(v[2], v[3]);
        *(uint2*)dst = pk;
      } else if (px0 < 258) {
        *(uint32_t*)dst = w0;
      }
    }
  }
}

// ---------------- fused up2x + lrelu/clamp + down2x, 8-row strips, 384 threads ----------------
// P2 v-split (zero duplication): group A (tid<131) v in [0,13), group B (tid 192..322)
// v in [13,26). Barriers are UNCONDITIONAL (outside all divergent control flow).
__global__ __launch_bounds__(384) void updown_kernel(
    const uint16_t* __restrict__ conv_outb,
    const float* __restrict__ upf, const float* __restrict__ dnf,
    uint16_t* __restrict__ down2b)
{
  __shared__ float Bp[26][268];                  // 27.9 KB
  __shared__ __align__(8) uint16_t Dpb[8][528];  // 8.4 KB
  __shared__ uint2 PpB[8][132];                  // 8.25 KB (B partials; [t][t2] layout)
  const int strip = blockIdx.x, c = blockIdx.y, b = blockIdx.z;
  const int y0 = strip * 8;
  const int tid = threadIdx.x;
  float fu[12], fd[12];
  #pragma unroll
  for (int k = 0; k < 12; ++k) { fu[k] = upf[11-k] * 2.0f; fd[k] = dnf[11-k]; }
  f32x2 fup[6];
  #pragma unroll
  for (int j = 0; j < 6; ++j) fup[j] = (f32x2){fu[2*j+1], fu[2*j]};
  if (tid < 260) {
    int r = tid / 10, pc = tid % 10;
    int col = (pc < 4) ? pc : (258 + pc);
    Bp[r][col] = 0.f;
  }
  const uint16_t* src = conv_outb + (size_t)(b*128 + c)*67080;

  // P1: vertical upsample, packed row-pairs; aligned dword loads (pair-merged).
  if (tid < 258) {
    const int m = tid;
    const int me = m & ~1;
    const uint32_t hi = (uint32_t)(m & 1);
    float a[18];
    #pragma unroll
    for (int r = 0; r < 18; ++r) {
      int gy = y0 - 4 + r;
      uint32_t wv = ((unsigned)gy < 258u)
                    ? *(const uint32_t*)(src + gy*260 + me) : 0u;
      a[r] = __uint_as_float((hi ? wv : (wv << 16)) & 0xFFFF0000u);
    }
    #pragma unroll
    for (int mp = 0; mp < 13; ++mp) {
      f32x2 sA = fup[0] * a[mp];     sA += fup[2] * a[mp + 2];  sA += fup[4] * a[mp + 4];
      f32x2 sB = fup[1] * a[mp + 1]; sB += fup[3] * a[mp + 3];  sB += fup[5] * a[mp + 5];
      f32x2 s2 = sA + sB;
      Bp[2*mp][m + 4]     = s2[0];
      Bp[2*mp + 1][m + 4] = s2[1];
    }
  }
  __syncthreads();

  // P2: q-pair horizontal upsample + lrelu + partial vertical downsample, v-split.
  const float LA = 0.84852813742386f;   // 0.6*sqrt(2)
  const float LB = 0.56568542494924f;   // 0.4*sqrt(2)
  const f32x2 cmin = {-256.f, -256.f}, cmax = {256.f, 256.f};
  const bool inA = tid < 131;
  const bool inB = (tid >= 192) && (tid < 323);
  const int t2 = inA ? tid : (inB ? (tid - 192) : 0);

#define P2PART(T2, VLO, VHI, DA, DB) {                                        \
    _Pragma("unroll")                                                         \
    for (int v = (VLO); v < (VHI); ++v) {                                     \
      float f[8];                                                             \
      _Pragma("unroll")                                                       \
      for (int j2 = 0; j2 < 4; ++j2)                                          \
        *(float2*)&f[2*j2] = *(const float2*)&Bp[v][2*(T2) + 2*j2];           \
      f32x2 ceA = fup[0]*f[0]; f32x2 ceB = fup[1]*f[1];                       \
      f32x2 coA = fup[0]*f[1]; f32x2 coB = fup[1]*f[2];                       \
      ceA += fup[2]*f[2];      ceB += fup[3]*f[3];                            \
      coA += fup[2]*f[3];      coB += fup[3]*f[4];                            \
      ceA += fup[4]*f[4];      ceB += fup[5]*f[5];                            \
      coA += fup[4]*f[5];      coB += fup[5]*f[6];                            \
      f32x2 ce = ceA + ceB, co = coA + coB;                                   \
      f32x2 abe, abo;                                                         \
      abe[0] = __builtin_fabsf(ce[0]); abe[1] = __builtin_fabsf(ce[1]);       \
      abo[0] = __builtin_fabsf(co[0]); abo[1] = __builtin_fabsf(co[1]);       \
      ce = LA*ce + LB*abe;                                                    \
      co = LA*co + LB*abo;                                                    \
      ce = __builtin_elementwise_min(__builtin_elementwise_max(ce, cmin), cmax); \
      co = __builtin_elementwise_min(__builtin_elementwise_max(co, cmin), cmax); \
      _Pragma("unroll")                                                       \
      for (int t = 0; t < 8; ++t) {                                           \
        const int k = v - 2*t;                                                \
        if (k >= 0 && k < 12) { DA[t] += fd[k]*ce; DB[t] += fd[k]*co; }       \
      }                                                                       \
    }                                                                         \
  }

  f32x2 dA[8], dB[8];
  #pragma unroll
  for (int t = 0; t < 8; ++t) { dA[t] = (f32x2){0.f,0.f}; dB[t] = (f32x2){0.f,0.f}; }
  if (inA) {
    P2PART(t2, 0, 13, dA, dB)
  }
  if (inB) {
    P2PART(t2, 13, 26, dA, dB)
    #pragma unroll
    for (int t = 0; t < 8; ++t) {
      uint2 st;
      st.x = cvtpk(dA[t][0], dA[t][1]);
      st.y = cvtpk(dB[t][0], dB[t][1]);
      PpB[t][t2] = st;
    }
  }
#undef P2PART
  __syncthreads();                       // uniform: B partials visible

  if (inA) {
    #pragma unroll
    for (int t = 0; t < 8; ++t) {
      uint2 pp = PpB[t][t2];
      f32x2 pA, pB;
      pA[0] = __uint_as_float(pp.x << 16);
      pA[1] = __uint_as_float(pp.x & 0xFFFF0000u);
      pB[0] = __uint_as_float(pp.y << 16);
      pB[1] = __uint_as_float(pp.y & 0xFFFF0000u);
      dA[t] += pA; dB[t] += pB;
      uint2 st;
      st.x = cvtpk(dA[t][0], dA[t][1]);
      st.y = cvtpk(dB[t][0], dB[t][1]);
      *(uint2*)&Dpb[t][4*t2] = st;
    }
  }
  __syncthreads();                       // uniform: Dpb ready

  // P3: horizontal downsample, bf16 LDS -> global bf16 (8 rows x 32 threads/row)
  if (tid < 256) {
    const int ty = tid >> 5, xg = tid & 31;
    const uint16_t* dprow = &Dpb[ty][0];
    uint32_t* dstrow = (uint32_t*)(down2b + ((size_t)(b*128 + c)*256 + (y0 + ty))*256);
    #pragma unroll
    for (int p = 0; p < 4; ++p) {
      const int pi = xg + 32*p;
      float fx[16];
      #pragma unroll
      for (int t = 0; t < 4; ++t) {
        uint2 wv = *(const uint2*)(dprow + 4*pi + 4*t);
        fx[4*t+0] = __uint_as_float(wv.x << 16);
        fx[4*t+1] = __uint_as_float(wv.x & 0xFFFF0000u);
        fx[4*t+2] = __uint_as_float(wv.y << 16);
        fx[4*t+3] = __uint_as_float(wv.y & 0xFFFF0000u);
      }
      float o0 = 0.f, o1 = 0.f;
      #pragma unroll
      for (int k = 0; k < 12; ++k) {
        o0 += fd[k] * fx[k];
        o1 += fd[k] * fx[k + 2];
      }
      dstrow[pi] = cvtpk(o0, o1);
    }
  }
}

// ---------------- rgb: bf16 down2 in, 4 px per thread ----------------
__global__ __launch_bounds__(128) void rgb_kernel(
    const uint16_t* __restrict__ down2b, const float* __restrict__ coef,
    const float* __restrict__ brgb, float* __restrict__ yout)
{
  __shared__ float cl[3][128];
  const int b = blockIdx.x >> 7;
  const int p4 = ((blockIdx.x & 127) << 7) + threadIdx.x;   // 4-px group 0..16383
  for (int e = threadIdx.x; e < 384; e += 128) cl[e >> 7][e & 127] = coef[b*384 + e];
  __syncthreads();
  f32x4 a0 = {0,0,0,0}, a1 = {0,0,0,0}, a2 = {0,0,0,0};
  const uint32_t* dsrc = (const uint32_t*)down2b + (size_t)b*4194304 + 2*p4;
  #pragma unroll 4
  for (int i = 0; i < 128; ++i) {
    uint2 wv = *(const uint2*)(dsrc + (size_t)i*32768);
    f32x4 v;
    v[0] = __uint_as_float(wv.x << 16);
    v[1] = __uint_as_float(wv.x & 0xFFFF0000u);
    v[2] = __uint_as_float(wv.y << 16);
    v[3] = __uint_as_float(wv.y & 0xFFFF0000u);
    a0 += cl[0][i]*v; a1 += cl[1][i]*v; a2 += cl[2][i]*v;
  }
  f32x4* yo = (f32x4*)yout;
  const float b0 = brgb[0], b1 = brgb[1], b2 = brgb[2];
  #pragma unroll
  for (int j = 0; j < 4; ++j) {
    a0[j] = fminf(fmaxf(a0[j] + b0, -256.f), 256.f);
    a1[j] = fminf(fmaxf(a1[j] + b1, -256.f), 256.f);
    a2[j] = fminf(fmaxf(a2[j] + b2, -256.f), 256.f);
  }
  yo[(size_t)(b*3 + 0)*16384 + p4] = a0;
  yo[(size_t)(b*3 + 1)*16384 + p4] = a1;
  yo[(size_t)(b*3 + 2)*16384 + p4] = a2;
}

extern "C" void kernel_launch(void* const* d_in, const int* in_sizes, int n_in,
                              void* d_out, int out_size, void* d_ws, size_t ws_size,
                              hipStream_t stream) {
  const float* x      = (const float*)d_in[0];
  const float* w      = (const float*)d_in[1];
  const float* afw    = (const float*)d_in[2];
  const float* afb    = (const float*)d_in[3];
  const float* wfeat  = (const float*)d_in[4];
  const float* bfeat  = (const float*)d_in[5];
  const float* argbw  = (const float*)d_in[6];
  const float* argbb  = (const float*)d_in[7];
  const float* wrgb   = (const float*)d_in[8];
  const float* brgb   = (const float*)d_in[9];
  const float* upf    = (const float*)d_in[10];
  const float* dnf    = (const float*)d_in[11];
  const float* emaf   = (const float*)d_in[12];
  const float* emar   = (const float*)d_in[13];

  float* ws = (float*)d_ws;
  size_t off = 0;
  float* s_feat   = ws + off; off += 256;
  float* coef     = ws + off; off += 768;
  float* sfeat_ws = ws + off; off += 256;
  float* srgb_ws  = ws + off; off += 256;
  float* partial  = ws + off; off += 16;
  short* wfrag    = (short*)(ws + off); off += 147456;             // 294912 bf16
  uint16_t* conv_outb = (uint16_t*)(ws + off); off += 8627840;     // 2*128*258*260 bf16
  uint16_t* down2b    = (uint16_t*)(ws + off); off += 8388608;     // 2*128*256*256 bf16
  if (ws_size < off * sizeof(float)) return;
  float* yout = (float*)d_out;

  prep1a_kernel<<<16, 256, 0, stream>>>(w, afw, afb, argbw, argbb, emar,
                                        sfeat_ws, srgb_ws, partial);
  prep1b_kernel<<<1, 256, 0, stream>>>(sfeat_ws, srgb_ws, wrgb, partial,
                                       s_feat, coef);
  prep2_kernel<<<256, 128, 0, stream>>>(wfeat, s_feat, emaf, wfrag);
  conv_mfma_kernel<<<dim3(9, 65, 2), 256, 0, stream>>>(x, wfrag, bfeat, conv_outb);
  updown_kernel<<<dim3(32, 128, 2), 384, 0, stream>>>(conv_outb, upf, dnf, down2b);
  rgb_kernel<<<256, 128, 0, stream>>>(down2b, coef, brgb, yout);
}

// Round 24
// 164.102 us; speedup vs baseline: 1.1280x; 1.1280x over previous
//
#include <hip/hip_runtime.h>
#include <hip/hip_bf16.h>
#include <cstdint>

typedef __attribute__((ext_vector_type(8))) short bf16x8;
typedef __attribute__((ext_vector_type(4))) float f32x4;
typedef __attribute__((ext_vector_type(2))) float f32x2;

__device__ inline uint16_t f2bf(float f) {
  uint32_t u = __float_as_uint(f);
  u += 0x7FFF + ((u >> 16) & 1);          // round-to-nearest-even
  return (uint16_t)(u >> 16);
}
// HW pair-pack: dst = [hi.bf16 : lo.bf16], RNE. Register-only asm (no mem hazard).
__device__ inline uint32_t cvtpk(float lo, float hi) {
  uint32_t r;
  asm("v_cvt_pk_bf16_f32 %0, %1, %2" : "=v"(r) : "v"(lo), "v"(hi));
  return r;
}

// ---------------- prep1a: parallel affine dots (16 blocks) ----------------
__global__ __launch_bounds__(256) void prep1a_kernel(
    const float* __restrict__ w,        // (2,512)
    const float* __restrict__ afw,      // (128,512)
    const float* __restrict__ afb,      // (128)
    const float* __restrict__ argbw,    // (128,512)
    const float* __restrict__ argbb,    // (128)
    const float* __restrict__ ema_r,    // (1)
    float* __restrict__ sfeat_ws,       // (256)
    float* __restrict__ srgb_ws,        // (256)
    float* __restrict__ partial)        // (16)
{
  __shared__ float psum[4];
  const int g = blockIdx.x;
  const int tid = threadIdx.x, lane = tid & 63, wv = tid >> 6;
  const float wg = 0.04419417382415922f;    // 1/sqrt(512)
  const float er = rsqrtf(ema_r[0]);
  float mysq = 0.f;
  #pragma unroll
  for (int i = 0; i < 4; ++i) {
    const int p = g*16 + wv*4 + i;
    const int bb = p >> 7, c = p & 127;
    float d1 = 0.f, d2 = 0.f;
    #pragma unroll
    for (int it = 0; it < 8; ++it) {
      const int k = lane + 64*it;
      const float wvv = w[bb*512 + k];
      d1 += wvv * afw[c*512 + k];
      d2 += wvv * argbw[c*512 + k];
    }
    #pragma unroll
    for (int off = 32; off; off >>= 1) {
      d1 += __shfl_xor(d1, off, 64);
      d2 += __shfl_xor(d2, off, 64);
    }
    const float sfeat = d1 * wg + afb[c];
    if (lane == 0) {
      sfeat_ws[p] = sfeat;
      srgb_ws[p]  = (d2 * wg + argbb[c]) * 0.08838834764831845f * er;
      mysq += sfeat * sfeat;
    }
  }
  if (lane == 0) psum[wv] = mysq;
  __syncthreads();
  if (tid == 0) partial[g] = psum[0] + psum[1] + psum[2] + psum[3];
}

// ---------------- prep1b: normalize s_feat + build rgb coefs ----------------
__global__ __launch_bounds__(256) void prep1b_kernel(
    const float* __restrict__ sfeat_ws, const float* __restrict__ srgb_ws,
    const float* __restrict__ wrgb, const float* __restrict__ partial,
    float* __restrict__ s_feat_out, float* __restrict__ coef_out)
{
  __shared__ float snorm_s;
  const int tid = threadIdx.x;
  if (tid == 0) {
    float s = 0.f;
    #pragma unroll
    for (int gg = 0; gg < 16; ++gg) s += partial[gg];
    snorm_s = rsqrtf(s * (1.0f/256.0f));
  }
  __syncthreads();
  const float snorm = snorm_s;
  s_feat_out[tid] = sfeat_ws[tid] * snorm;
  for (int e = tid; e < 768; e += 256) {
    int bb = e / 384, o = (e % 384) / 128, i = e & 127;
    coef_out[e] = wrgb[o*128 + i] * srgb_ws[bb*128 + i];
  }
}

// ---------------- prep2: wnscale (inline) + modulate + demod -> bf16 fragments ----------------
__global__ __launch_bounds__(128) void prep2_kernel(
    const float* __restrict__ wfeat, const float* __restrict__ s_feat,
    const float* __restrict__ ema_f, short* __restrict__ wfrag)
{
  __shared__ float red[128];
  const int bo = blockIdx.x, b = bo >> 7, o = bo & 127;
  const int i = threadIdx.x;
  float wraw[9]; float ssr = 0.f;
  #pragma unroll
  for (int j = 0; j < 9; ++j) { wraw[j] = wfeat[(o*128 + i)*9 + j]; ssr += wraw[j]*wraw[j]; }
  red[i] = ssr; __syncthreads();
  for (int off = 64; off > 0; off >>= 1) { if (i < off) red[i] += red[i+off]; __syncthreads(); }
  const float wsc = rsqrtf(red[0] * (1.0f/1152.0f));
  const float sv = s_feat[b*128 + i];
  float wr[9]; float ss = 0.f;
  #pragma unroll
  for (int j = 0; j < 9; ++j) { wr[j] = wraw[j] * wsc * sv; ss += wr[j]*wr[j]; }
  __syncthreads();
  red[i] = ss; __syncthreads();
  for (int off = 64; off > 0; off >>= 1) { if (i < off) red[i] += red[i+off]; __syncthreads(); }
  const float d = rsqrtf(red[0] + 1e-8f) * rsqrtf(ema_f[0]);
  const int chunk = i >> 5;
  const int lane = (o & 15) | (((i >> 3) & 3) << 4);
  const int jj = i & 7;
  #pragma unroll
  for (int tap = 0; tap < 9; ++tap) {
    int kidx = chunk*9 + tap;
    size_t sidx = ((((size_t)b*36 + kidx)*8 + (o >> 4)) << 9) + (lane << 3) + jj;
    wfrag[sidx] = (short)f2bf(wr[tap] * d);
  }
}

// ---------------- conv via bf16 MFMA implicit GEMM ----------------
// bf16 output, 260-col padded rows; staging/epilogue packs via v_cvt_pk_bf16_f32.
__global__ __launch_bounds__(256, 3) void conv_mfma_kernel(
    const float* __restrict__ x, const short* __restrict__ wfrag,
    const float* __restrict__ bias_feat, uint16_t* __restrict__ conv_outb)
{
  __shared__ __align__(16) char xls[52224];
  __shared__ float bias_lds[128];
  const int tid = threadIdx.x;
  const int bx = blockIdx.x, by = blockIdx.y, b = blockIdx.z;
  const int x0 = bx * 32, y0 = by * 4;
  if (tid < 128) bias_lds[tid] = bias_feat[tid];

  const f32x4 f4z = {0.f, 0.f, 0.f, 0.f};
  const float* xb = x + (size_t)b * 8388608;

  {
    const int sl = tid & 7, pL = tid >> 3;
    const int gxm = x0 + 4*sl;
    const bool xokm = (unsigned)gxm <= 252u;
    const int gxe = x0 - 2;
    #pragma unroll
    for (int r = 0; r < 6; ++r) {
      const int gy = y0 - 2 + r;
      const bool yok = (unsigned)gy < 256u;
      #pragma unroll
      for (int ph = 0; ph < 2; ++ph) {
        const int p = pL + 32*ph;
        const float* s0 = xb + (size_t)(2*p)*65536 + gy*256 + gxm;
        const bool ok = yok && xokm;
        f32x4 v0 = ok ? *(const f32x4*)s0 : f4z;
        f32x4 v1 = ok ? *(const f32x4*)(s0 + 65536) : f4z;
        char* wb = xls + (size_t)(((r*16 + (p>>2))*34 + 2 + 4*sl)*16 + (p&3)*4);
        #pragma unroll
        for (int i2 = 0; i2 < 4; ++i2)
          *(uint32_t*)(wb + i2*16) = cvtpk(v0[i2], v1[i2]);
        if (sl == 0) {
          const bool eok = yok && (gxe >= 0);
          const float* e0 = xb + (size_t)(2*p)*65536 + gy*256 + gxe;
          float e00 = eok ? e0[0] : 0.f, e01 = eok ? e0[1] : 0.f;
          float e10 = eok ? e0[65536] : 0.f, e11 = eok ? e0[65537] : 0.f;
          char* eb = xls + (size_t)(((r*16 + (p>>2))*34)*16 + (p&3)*4);
          *(uint32_t*)eb        = cvtpk(e00, e10);
          *(uint32_t*)(eb + 16) = cvtpk(e01, e11);
        }
      }
    }
  }
  __syncthreads();

  const int lane = tid & 63, wave = tid >> 6;
  const int wp = wave & 1, wo = wave >> 1;
  const int l15 = lane & 15, lq = lane >> 4;
  const short* wbase = wfrag + ((size_t)b*288 + wo*4)*512 + (size_t)lane*8;
  const int abase = ((wp*32 + lq)*34 + l15)*16;

  f32x4 acc[4][4] = {};
  bf16x8 wfA[4], wfB[4], wfC[4];

#define LDW(KI, WF) { const short* wp_ = wbase + (size_t)(KI)*4096;          \
    WF[0] = *(const bf16x8*)(wp_);       WF[1] = *(const bf16x8*)(wp_+512);  \
    WF[2] = *(const bf16x8*)(wp_+1024);  WF[3] = *(const bf16x8*)(wp_+1536); }

#define MFX(KI, WF) {                                                         \
    const int ch_ = (KI)/9, tp_ = (KI)%9, ky_ = tp_/3, kx_ = tp_%3;           \
    const int o00 = ((ky_*16 + ch_*4)*34 + kx_)*16;                           \
    const int o10 = o00 + 8704;                                               \
    bf16x8 xf0 = *(const bf16x8*)(xls + abase + o00);                         \
    bf16x8 xf1 = *(const bf16x8*)(xls + abase + o00 + 256);                   \
    bf16x8 xf2 = *(const bf16x8*)(xls + abase + o10);                         \
    bf16x8 xf3 = *(const bf16x8*)(xls + abase + o10 + 256);                   \
    __builtin_amdgcn_s_setprio(1);                                            \
    acc[0][0] = __builtin_amdgcn_mfma_f32_16x16x32_bf16(xf0, WF[0], acc[0][0], 0,0,0); \
    acc[0][1] = __builtin_amdgcn_mfma_f32_16x16x32_bf16(xf0, WF[1], acc[0][1], 0,0,0); \
    acc[0][2] = __builtin_amdgcn_mfma_f32_16x16x32_bf16(xf0, WF[2], acc[0][2], 0,0,0); \
    acc[0][3] = __builtin_amdgcn_mfma_f32_16x16x32_bf16(xf0, WF[3], acc[0][3], 0,0,0); \
    acc[1][0] = __builtin_amdgcn_mfma_f32_16x16x32_bf16(xf1, WF[0], acc[1][0], 0,0,0); \
    acc[1][1] = __builtin_amdgcn_mfma_f32_16x16x32_bf16(xf1, WF[1], acc[1][1], 0,0,0); \
    acc[1][2] = __builtin_amdgcn_mfma_f32_16x16x32_bf16(xf1, WF[2], acc[1][2], 0,0,0); \
    acc[1][3] = __builtin_amdgcn_mfma_f32_16x16x32_bf16(xf1, WF[3], acc[1][3], 0,0,0); \
    acc[2][0] = __builtin_amdgcn_mfma_f32_16x16x32_bf16(xf2, WF[0], acc[2][0], 0,0,0); \
    acc[2][1] = __builtin_amdgcn_mfma_f32_16x16x32_bf16(xf2, WF[1], acc[2][1], 0,0,0); \
    acc[2][2] = __builtin_amdgcn_mfma_f32_16x16x32_bf16(xf2, WF[2], acc[2][2], 0,0,0); \
    acc[2][3] = __builtin_amdgcn_mfma_f32_16x16x32_bf16(xf2, WF[3], acc[2][3], 0,0,0); \
    acc[3][0] = __builtin_amdgcn_mfma_f32_16x16x32_bf16(xf3, WF[0], acc[3][0], 0,0,0); \
    acc[3][1] = __builtin_amdgcn_mfma_f32_16x16x32_bf16(xf3, WF[1], acc[3][1], 0,0,0); \
    acc[3][2] = __builtin_amdgcn_mfma_f32_16x16x32_bf16(xf3, WF[2], acc[3][2], 0,0,0); \
    acc[3][3] = __builtin_amdgcn_mfma_f32_16x16x32_bf16(xf3, WF[3], acc[3][3], 0,0,0); \
    __builtin_amdgcn_s_setprio(0); }

  LDW(0, wfA); LDW(1, wfB); LDW(2, wfC);
  #pragma unroll
  for (int kk = 0; kk < 36; kk += 3) {
    MFX(kk, wfA);
    if (kk + 3 < 36) LDW(kk + 3, wfA);
    MFX(kk + 1, wfB);
    if (kk + 4 < 36) LDW(kk + 4, wfB);
    MFX(kk + 2, wfC);
    if (kk + 5 < 36) LDW(kk + 5, wfC);
  }
#undef LDW
#undef MFX

  // epilogue: bf16 pack via cvt_pk, aligned uint2 stores (row stride 260)
  #pragma unroll
  for (int p = 0; p < 4; ++p) {
    const int py = y0 + wp*2 + (p>>1);
    if (py >= 258) continue;
    const int px0 = x0 + (p&1)*16 + lq*4;
    #pragma unroll
    for (int o = 0; o < 4; ++o) {
      const int oc = wo*64 + o*16 + l15;
      const float bz = bias_lds[oc];
      f32x4 v = acc[p][o];
      v[0] += bz; v[1] += bz; v[2] += bz; v[3] += bz;
      uint16_t* dst = conv_outb + (size_t)(b*128 + oc)*67080 + (size_t)py*260 + px0;
      uint32_t w0 = cvtpk(v[0], v[1]);
      if (px0 <= 254) {
        uint2 pk; pk.x = w0; pk.y = cvtpk(v[2], v[3]);
        *(uint2*)dst = pk;
      } else if (px0 < 258) {
        *(uint32_t*)dst = w0;
      }
    }
  }
}

// ---------------- fused up2x + lrelu/clamp + down2x, 8-row strips ----------------
// bf16 in (aligned dword loads), Dp handoff in bf16 LDS (36.3 KB total -> 4 blocks/CU),
// packed clamps, cvt_pk packing.  (r21 form — proven best.)
__global__ __launch_bounds__(256) void updown_kernel(
    const uint16_t* __restrict__ conv_outb,
    const float* __restrict__ upf, const float* __restrict__ dnf,
    uint16_t* __restrict__ down2b)
{
  __shared__ float Bp[26][268];               // 27.9 KB
  __shared__ __align__(8) uint16_t Dpb[8][528];  // 8.4 KB (522 live cols + pad)
  const int strip = blockIdx.x, c = blockIdx.y, b = blockIdx.z;
  const int y0 = strip * 8;
  const int tid = threadIdx.x;
  float fu[12], fd[12];
  #pragma unroll
  for (int k = 0; k < 12; ++k) { fu[k] = upf[11-k] * 2.0f; fd[k] = dnf[11-k]; }
  f32x2 fup[6];
  #pragma unroll
  for (int j = 0; j < 6; ++j) fup[j] = (f32x2){fu[2*j+1], fu[2*j]};
  for (int e = tid; e < 260; e += 256) {
    int r = e / 10, pc = e % 10;
    int col = (pc < 4) ? pc : (258 + pc);
    Bp[r][col] = 0.f;
  }
  const uint16_t* src = conv_outb + (size_t)(b*128 + c)*67080;

  // P1: vertical upsample, packed row-pairs; aligned dword loads (pair-merged).
  #pragma unroll 1
  for (int m = tid; m < 258; m += 256) {
    const int me = m & ~1;
    const uint32_t hi = (uint32_t)(m & 1);
    float a[18];
    #pragma unroll
    for (int r = 0; r < 18; ++r) {
      int gy = y0 - 4 + r;
      uint32_t wv = ((unsigned)gy < 258u)
                    ? *(const uint32_t*)(src + gy*260 + me) : 0u;
      a[r] = __uint_as_float((hi ? wv : (wv << 16)) & 0xFFFF0000u);
    }
    #pragma unroll
    for (int mp = 0; mp < 13; ++mp) {
      f32x2 sA = fup[0] * a[mp];     sA += fup[2] * a[mp + 2];  sA += fup[4] * a[mp + 4];
      f32x2 sB = fup[1] * a[mp + 1]; sB += fup[3] * a[mp + 3];  sB += fup[5] * a[mp + 5];
      f32x2 s2 = sA + sB;
      Bp[2*mp][m + 4]     = s2[0];
      Bp[2*mp + 1][m + 4] = s2[1];
    }
  }
  __syncthreads();

  // P2: q-pair horizontal upsample + lrelu + streaming vertical downsample.
  const float LA = 0.84852813742386f;   // 0.6*sqrt(2)
  const float LB = 0.56568542494924f;   // 0.4*sqrt(2)
  const f32x2 cmin = {-256.f, -256.f}, cmax = {256.f, 256.f};
  if (tid < 131) {
    const int t2 = tid;
    f32x2 dA[8], dB[8];
    #pragma unroll
    for (int t = 0; t < 8; ++t) { dA[t] = (f32x2){0.f,0.f}; dB[t] = (f32x2){0.f,0.f}; }
    #pragma unroll
    for (int v = 0; v < 26; ++v) {
      float f[8];
      #pragma unroll
      for (int j2 = 0; j2 < 4; ++j2)
        *(float2*)&f[2*j2] = *(const float2*)&Bp[v][2*t2 + 2*j2];
      f32x2 ceA = fup[0]*f[0]; f32x2 ceB = fup[1]*f[1];
      f32x2 coA = fup[0]*f[1]; f32x2 coB = fup[1]*f[2];
      ceA += fup[2]*f[2];      ceB += fup[3]*f[3];
      coA += fup[2]*f[3];      coB += fup[3]*f[4];
      ceA += fup[4]*f[4];      ceB += fup[5]*f[5];
      coA += fup[4]*f[5];      coB += fup[5]*f[6];
      f32x2 ce = ceA + ceB, co = coA + coB;
      f32x2 abe, abo;
      abe[0] = __builtin_fabsf(ce[0]); abe[1] = __builtin_fabsf(ce[1]);
      abo[0] = __builtin_fabsf(co[0]); abo[1] = __builtin_fabsf(co[1]);
      ce = LA*ce + LB*abe;
      co = LA*co + LB*abo;
      ce = __builtin_elementwise_min(__builtin_elementwise_max(ce, cmin), cmax);
      co = __builtin_elementwise_min(__builtin_elementwise_max(co, cmin), cmax);
      #pragma unroll
      for (int t = 0; t < 8; ++t) {
        const int k = v - 2*t;                 // compile-time under full unroll
        if (k >= 0 && k < 12) { dA[t] += fd[k]*ce; dB[t] += fd[k]*co; }
      }
    }
    #pragma unroll
    for (int t = 0; t < 8; ++t) {
      uint2 st;
      st.x = cvtpk(dA[t][0], dA[t][1]);
      st.y = cvtpk(dB[t][0], dB[t][1]);
      *(uint2*)&Dpb[t][4*t2] = st;             // 8B-aligned
    }
  }
  __syncthreads();

  // P3: horizontal downsample, bf16 LDS -> global bf16 (8 rows x 32 threads/row)
  {
    const int ty = tid >> 5, xg = tid & 31;
    const uint16_t* dprow = &Dpb[ty][0];
    uint32_t* dstrow = (uint32_t*)(down2b + ((size_t)(b*128 + c)*256 + (y0 + ty))*256);
    #pragma unroll
    for (int p = 0; p < 4; ++p) {
      const int pi = xg + 32*p;
      float fx[16];
      #pragma unroll
      for (int t = 0; t < 4; ++t) {
        uint2 wv = *(const uint2*)(dprow + 4*pi + 4*t);
        fx[4*t+0] = __uint_as_float(wv.x << 16);
        fx[4*t+1] = __uint_as_float(wv.x & 0xFFFF0000u);
        fx[4*t+2] = __uint_as_float(wv.y << 16);
        fx[4*t+3] = __uint_as_float(wv.y & 0xFFFF0000u);
      }
      float o0 = 0.f, o1 = 0.f;
      #pragma unroll
      for (int k = 0; k < 12; ++k) {
        o0 += fd[k] * fx[k];
        o1 += fd[k] * fx[k + 2];
      }
      dstrow[pi] = cvtpk(o0, o1);
    }
  }
}

// ---------------- rgb: bf16 down2 in, 4 px per thread ----------------
__global__ __launch_bounds__(128) void rgb_kernel(
    const uint16_t* __restrict__ down2b, const float* __restrict__ coef,
    const float* __restrict__ brgb, float* __restrict__ yout)
{
  __shared__ float cl[3][128];
  const int b = blockIdx.x >> 7;
  const int p4 = ((blockIdx.x & 127) << 7) + threadIdx.x;   // 4-px group 0..16383
  for (int e = threadIdx.x; e < 384; e += 128) cl[e >> 7][e & 127] = coef[b*384 + e];
  __syncthreads();
  f32x4 a0 = {0,0,0,0}, a1 = {0,0,0,0}, a2 = {0,0,0,0};
  const uint32_t* dsrc = (const uint32_t*)down2b + (size_t)b*4194304 + 2*p4;
  #pragma unroll 4
  for (int i = 0; i < 128; ++i) {
    uint2 wv = *(const uint2*)(dsrc + (size_t)i*32768);
    f32x4 v;
    v[0] = __uint_as_float(wv.x << 16);
    v[1] = __uint_as_float(wv.x & 0xFFFF0000u);
    v[2] = __uint_as_float(wv.y << 16);
    v[3] = __uint_as_float(wv.y & 0xFFFF0000u);
    a0 += cl[0][i]*v; a1 += cl[1][i]*v; a2 += cl[2][i]*v;
  }
  f32x4* yo = (f32x4*)yout;
  const float b0 = brgb[0], b1 = brgb[1], b2 = brgb[2];
  #pragma unroll
  for (int j = 0; j < 4; ++j) {
    a0[j] = fminf(fmaxf(a0[j] + b0, -256.f), 256.f);
    a1[j] = fminf(fmaxf(a1[j] + b1, -256.f), 256.f);
    a2[j] = fminf(fmaxf(a2[j] + b2, -256.f), 256.f);
  }
  yo[(size_t)(b*3 + 0)*16384 + p4] = a0;
  yo[(size_t)(b*3 + 1)*16384 + p4] = a1;
  yo[(size_t)(b*3 + 2)*16384 + p4] = a2;
}

extern "C" void kernel_launch(void* const* d_in, const int* in_sizes, int n_in,
                              void* d_out, int out_size, void* d_ws, size_t ws_size,
                              hipStream_t stream) {
  const float* x      = (const float*)d_in[0];
  const float* w      = (const float*)d_in[1];
  const float* afw    = (const float*)d_in[2];
  const float* afb    = (const float*)d_in[3];
  const float* wfeat  = (const float*)d_in[4];
  const float* bfeat  = (const float*)d_in[5];
  const float* argbw  = (const float*)d_in[6];
  const float* argbb  = (const float*)d_in[7];
  const float* wrgb   = (const float*)d_in[8];
  const float* brgb   = (const float*)d_in[9];
  const float* upf    = (const float*)d_in[10];
  const float* dnf    = (const float*)d_in[11];
  const float* emaf   = (const float*)d_in[12];
  const float* emar   = (const float*)d_in[13];

  float* ws = (float*)d_ws;
  size_t off = 0;
  float* s_feat   = ws + off; off += 256;
  float* coef     = ws + off; off += 768;
  float* sfeat_ws = ws + off; off += 256;
  float* srgb_ws  = ws + off; off += 256;
  float* partial  = ws + off; off += 16;
  short* wfrag    = (short*)(ws + off); off += 147456;             // 294912 bf16
  uint16_t* conv_outb = (uint16_t*)(ws + off); off += 8627840;     // 2*128*258*260 bf16
  uint16_t* down2b    = (uint16_t*)(ws + off); off += 8388608;     // 2*128*256*256 bf16
  if (ws_size < off * sizeof(float)) return;
  float* yout = (float*)d_out;

  prep1a_kernel<<<16, 256, 0, stream>>>(w, afw, afb, argbw, argbb, emar,
                                        sfeat_ws, srgb_ws, partial);
  prep1b_kernel<<<1, 256, 0, stream>>>(sfeat_ws, srgb_ws, wrgb, partial,
                                       s_feat, coef);
  prep2_kernel<<<256, 128, 0, stream>>>(wfeat, s_feat, emaf, wfrag);
  conv_mfma_kernel<<<dim3(9, 65, 2), 256, 0, stream>>>(x, wfrag, bfeat, conv_outb);
  updown_kernel<<<dim3(32, 128, 2), 256, 0, stream>>>(conv_outb, upf, dnf, down2b);
  rgb_kernel<<<256, 128, 0, stream>>>(down2b, coef, brgb, yout);
}